// Round 1
// baseline (1404.373 us; speedup 1.0000x reference)
//
#include <hip/hip_runtime.h>
#include <float.h>
#include <math.h>

#define BCLOUDS 16
#define PPTS    1024
#define NPTS    (BCLOUDS * PPTS)
#define KNB     32
#define NCLS    40

// ---------------------------------------------------------------------------
// kNN: 4 query rows per block (256 threads). Distances into LDS, then one
// wave per row does 32x register-resident argmin with 64-lane butterfly.
// ---------------------------------------------------------------------------
template<int F>
__global__ __launch_bounds__(256) void knn_kernel(const float* __restrict__ x,
                                                  int* __restrict__ nbr) {
    __shared__ float xp[4][F];
    __shared__ float dmat[4][PPTS];
    const int tid  = threadIdx.x;
    const int p0   = blockIdx.x * 4;      // first global row of this block
    const int cloud = p0 >> 10;
    const int pl0  = p0 & 1023;           // local row base within the cloud
    const float* xc = x + (size_t)cloud * PPTS * F;

    // load 4 query rows into LDS
    for (int i = tid; i < 4 * F; i += 256)
        xp[i / F][i % F] = xc[(size_t)(pl0 + i / F) * F + (i % F)];
    __syncthreads();

    // distance computation: each thread handles 4 candidate points q
    for (int j = 0; j < 4; ++j) {
        const int q = tid + j * 256;
        float acc[4] = {0.f, 0.f, 0.f, 0.f};
        if constexpr (F % 4 == 0) {
            const float4* xq4 = reinterpret_cast<const float4*>(xc + (size_t)q * F);
            for (int f4 = 0; f4 < F / 4; ++f4) {
                const float4 v = xq4[f4];
#pragma unroll
                for (int r = 0; r < 4; ++r) {
                    const float4 pv = reinterpret_cast<const float4*>(xp[r])[f4];
                    const float d0 = v.x - pv.x, d1 = v.y - pv.y;
                    const float d2 = v.z - pv.z, d3 = v.w - pv.w;
                    acc[r] += d0 * d0 + d1 * d1 + d2 * d2 + d3 * d3;
                }
            }
        } else {
            const float* xq = xc + (size_t)q * F;
            for (int f = 0; f < F; ++f) {
                const float v = xq[f];
#pragma unroll
                for (int r = 0; r < 4; ++r) { const float df = v - xp[r][f]; acc[r] += df * df; }
            }
        }
#pragma unroll
        for (int r = 0; r < 4; ++r)
            dmat[r][q] = (q == pl0 + r) ? FLT_MAX : acc[r];
    }
    __syncthreads();

    // selection: wave w owns row w; values live in registers
    const int wave = tid >> 6, lane = tid & 63;
    float vals[16];
#pragma unroll
    for (int i = 0; i < 16; ++i) vals[i] = dmat[wave][lane + i * 64];

    int* out = nbr + (size_t)(p0 + wave) * KNB;
    for (int it = 0; it < KNB; ++it) {
        float bv = vals[0];
        int bq = lane;
#pragma unroll
        for (int i = 1; i < 16; ++i) {
            const float v = vals[i];
            if (v < bv) { bv = v; bq = lane + i * 64; }   // ascending i => smaller q kept on tie
        }
        // 64-lane butterfly min on (v, q), tie -> smaller q; all lanes converge
#pragma unroll
        for (int off = 1; off < 64; off <<= 1) {
            const float ov = __shfl_xor(bv, off);
            const int   oq = __shfl_xor(bq, off);
            if (ov < bv || (ov == bv && oq < bq)) { bv = ov; bq = oq; }
        }
        if (lane == 0) out[it] = cloud * PPTS + bq;
        // remove winner (static indices only — avoid scratch spill)
        const int vl = bq & 63, vi = bq >> 6;
#pragma unroll
        for (int i = 0; i < 16; ++i)
            if (lane == vl && vi == i) vals[i] = FLT_MAX;
    }
}

// ---------------------------------------------------------------------------
// Edge GEMM: A = x @ (W_top - W_bot) + b ; Bm = x @ W_bot
// 16 rows per block; weights read once per f, rows accumulated in registers.
// ---------------------------------------------------------------------------
template<int F, int FO>
__global__ __launch_bounds__(256) void edge_gemm_kernel(const float* __restrict__ x,
                                                        const float* __restrict__ W,
                                                        const float* __restrict__ bias,
                                                        float* __restrict__ A,
                                                        float* __restrict__ Bm) {
    constexpr int RT  = 16;
    constexpr int RS  = 256 / FO;   // rows covered in parallel by the block
    constexpr int RPT = RT / RS;    // rows per thread
    __shared__ float xs[RT][F];
    const int tid = threadIdx.x;
    const int n0  = blockIdx.x * RT;
    for (int i = tid; i < RT * F; i += 256)
        xs[i / F][i % F] = x[(size_t)n0 * F + i];
    __syncthreads();

    const int o  = tid % FO;
    const int r0 = tid / FO;
    float accA[RPT], accB[RPT];
#pragma unroll
    for (int i = 0; i < RPT; ++i) { accA[i] = 0.f; accB[i] = 0.f; }

    for (int f = 0; f < F; ++f) {
        const float wt = W[(size_t)f * FO + o];
        const float wb = W[(size_t)(F + f) * FO + o];
        const float wd = wt - wb;
#pragma unroll
        for (int i = 0; i < RPT; ++i) {
            const float xv = xs[r0 + i * RS][f];
            accA[i] = fmaf(xv, wd, accA[i]);
            accB[i] = fmaf(xv, wb, accB[i]);
        }
    }
    const float bo = bias[o];
#pragma unroll
    for (int i = 0; i < RPT; ++i) {
        const size_t row = (size_t)(n0 + r0 + i * RS);
        A[row * FO + o]  = accA[i] + bo;
        Bm[row * FO + o] = accB[i];
    }
}

// ---------------------------------------------------------------------------
// Combine: x_out[n,o] = relu(A[n,o] + max_k Bm[nbr[n,k],o])   (bias already in A)
// ---------------------------------------------------------------------------
template<int FO>
__global__ __launch_bounds__(256) void combine_kernel(const float* __restrict__ A,
                                                      const float* __restrict__ Bm,
                                                      const int* __restrict__ nbr,
                                                      float* __restrict__ xout) {
    const int idx = blockIdx.x * 256 + threadIdx.x;   // over N*FO
    const int n = idx / FO;
    const int o = idx % FO;
    const int* nb = nbr + (size_t)n * KNB;
    float m = -FLT_MAX;
#pragma unroll 8
    for (int k = 0; k < KNB; ++k)
        m = fmaxf(m, Bm[(size_t)nb[k] * FO + o]);
    const float v = A[idx] + m;
    xout[idx] = v > 0.f ? v : 0.f;
}

// ---------------------------------------------------------------------------
// Classifier: one wave per point. logits (40) in lanes, shuffle softmax,
// per-row -logp into lossbuf; probs written to d_out+1.
// ---------------------------------------------------------------------------
__global__ __launch_bounds__(256) void classifier_kernel(const float* __restrict__ x,
                                                         const float* __restrict__ Wc,
                                                         const float* __restrict__ bc,
                                                         const int* __restrict__ target,
                                                         float* __restrict__ probs,
                                                         float* __restrict__ lossbuf) {
    const int tid = threadIdx.x;
    const int lane = tid & 63;
    const int n = blockIdx.x * 4 + (tid >> 6);
    const float* xr = x + (size_t)n * 256;
    float logit = -FLT_MAX;
    if (lane < NCLS) {
        float acc = bc[lane];
        for (int f = 0; f < 256; ++f)
            acc = fmaf(xr[f], Wc[f * NCLS + lane], acc);
        logit = acc;
    }
    float m = logit;
#pragma unroll
    for (int off = 32; off; off >>= 1) m = fmaxf(m, __shfl_xor(m, off));
    const float e = (lane < NCLS) ? __expf(logit - m) : 0.f;
    float s = e;
#pragma unroll
    for (int off = 32; off; off >>= 1) s += __shfl_xor(s, off);
    if (lane < NCLS) probs[(size_t)n * NCLS + lane] = e / s;
    const float lt = __shfl(logit, target[n]);
    if (lane == 0) lossbuf[n] = logf(s) - (lt - m);   // -logp[target]
}

// deterministic mean over NPTS values -> out[0]
__global__ __launch_bounds__(256) void loss_reduce_kernel(const float* __restrict__ lossbuf,
                                                          float* __restrict__ out) {
    __shared__ float s[256];
    float acc = 0.f;
    for (int i = threadIdx.x; i < NPTS; i += 256) acc += lossbuf[i];
    s[threadIdx.x] = acc;
    __syncthreads();
    for (int off = 128; off; off >>= 1) {
        if (threadIdx.x < off) s[threadIdx.x] += s[threadIdx.x + off];
        __syncthreads();
    }
    if (threadIdx.x == 0) out[0] = s[0] / (float)NPTS;
}

extern "C" void kernel_launch(void* const* d_in, const int* in_sizes, int n_in,
                              void* d_out, int out_size, void* d_ws, size_t ws_size,
                              hipStream_t stream) {
    (void)in_sizes; (void)n_in; (void)out_size; (void)ws_size;
    const float* x_in   = (const float*)d_in[0];
    const int*   target = (const int*)d_in[2];
    const float* W1 = (const float*)d_in[3];
    const float* b1 = (const float*)d_in[4];
    const float* W2 = (const float*)d_in[5];
    const float* b2 = (const float*)d_in[6];
    const float* W3 = (const float*)d_in[7];
    const float* b3 = (const float*)d_in[8];
    const float* Wc = (const float*)d_in[9];
    const float* bc = (const float*)d_in[10];

    char* ws = (char*)d_ws;
    float* X       = (float*)(ws);                                // N*256 f32 (ping)
    float* A       = (float*)(ws + (size_t)16 * 1024 * 1024);     // N*256 f32
    float* Bm      = (float*)(ws + (size_t)32 * 1024 * 1024);     // N*256 f32
    int*   nbr     = (int*)  (ws + (size_t)48 * 1024 * 1024);     // N*32 int
    float* lossbuf = (float*)(ws + (size_t)50 * 1024 * 1024);     // N f32

    float* outF  = (float*)d_out;
    float* probs = outF + 1;

    // ---- layer 1 (F=3 -> 64) ----
    knn_kernel<3><<<NPTS / 4, 256, 0, stream>>>(x_in, nbr);
    edge_gemm_kernel<3, 64><<<NPTS / 16, 256, 0, stream>>>(x_in, W1, b1, A, Bm);
    combine_kernel<64><<<NPTS * 64 / 256, 256, 0, stream>>>(A, Bm, nbr, X);

    // ---- layer 2 (64 -> 128) ----
    knn_kernel<64><<<NPTS / 4, 256, 0, stream>>>(X, nbr);
    edge_gemm_kernel<64, 128><<<NPTS / 16, 256, 0, stream>>>(X, W2, b2, A, Bm);
    combine_kernel<128><<<NPTS * 128 / 256, 256, 0, stream>>>(A, Bm, nbr, X);

    // ---- layer 3 (128 -> 256) ----
    knn_kernel<128><<<NPTS / 4, 256, 0, stream>>>(X, nbr);
    edge_gemm_kernel<128, 256><<<NPTS / 16, 256, 0, stream>>>(X, W3, b3, A, Bm);
    combine_kernel<256><<<NPTS * 256 / 256, 256, 0, stream>>>(A, Bm, nbr, X);

    // ---- classifier + loss ----
    classifier_kernel<<<NPTS / 4, 256, 0, stream>>>(X, Wc, bc, target, probs, lossbuf);
    loss_reduce_kernel<<<1, 256, 0, stream>>>(lossbuf, outF);
}

// Round 3
// 624.615 us; speedup vs baseline: 2.2484x; 2.2484x over previous
//
#include <hip/hip_runtime.h>
#include <float.h>
#include <math.h>

#define BCLOUDS 16
#define PPTS    1024
#define NPTS    (BCLOUDS * PPTS)
#define KNB     32
#define NCLS    40
#define RPB     8                  // rows per knn block
#define NBIN    512                // histogram bins
#define HPAD    (NBIN + NBIN / 16) // +1 word pad every 16 -> conflict-light scan
#define SELFM   0xFFFFFFFFu        // self marker: above every real distance bit pattern

__device__ __forceinline__ int hidx(int b) { return b + (b >> 4); }

// ---------------------------------------------------------------------------
// kNN: 8 rows/block. Distances via norm identity (self-dots fused in-register),
// then per-wave histogram radix select with per-pass adaptive (base, shift).
// Invariants: real candidates never clamp; self marker never selectable;
// span shrinks >=256x per pass -> terminates in <=~5 passes.
// ---------------------------------------------------------------------------
template<int F>
__global__ __launch_bounds__(256) void knn_kernel(const float* __restrict__ x,
                                                  int* __restrict__ nbr) {
    __shared__ unsigned dmat[RPB][PPTS];
    __shared__ float    xp[RPB][F];
    __shared__ float    rn[RPB];
    __shared__ unsigned hist[4][HPAD];
    __shared__ unsigned bcast[4];

    const int tid   = threadIdx.x;
    const int lane  = tid & 63;
    const int wave  = tid >> 6;
    const int bpc   = PPTS / RPB;
    const int cloud = blockIdx.x / bpc;
    const int pl0   = (blockIdx.x % bpc) * RPB;
    const float* xc = x + (size_t)cloud * PPTS * F;

    for (int i = tid; i < RPB * F; i += 256)
        xp[i / F][i % F] = xc[(size_t)(pl0 + i / F) * F + (i % F)];
    __syncthreads();
    if (tid < RPB) {
        float s = 0.f;
        for (int f = 0; f < F; ++f) { const float v = xp[tid][f]; s = fmaf(v, v, s); }
        rn[tid] = s;
    }
    __syncthreads();

    // ---- distances: thread owns candidates q = tid + c*256, c<4 ----
    float acc[RPB][4];
    float qnv[4];
#pragma unroll
    for (int c = 0; c < 4; ++c) qnv[c] = 0.f;
#pragma unroll
    for (int r = 0; r < RPB; ++r)
#pragma unroll
        for (int c = 0; c < 4; ++c) acc[r][c] = 0.f;

    if constexpr (F % 4 == 0) {
        const float4* xc4 = reinterpret_cast<const float4*>(xc);
#pragma unroll 2
        for (int f4 = 0; f4 < F / 4; ++f4) {
            float4 vq[4];
#pragma unroll
            for (int c = 0; c < 4; ++c) vq[c] = xc4[(size_t)(tid + c * 256) * (F / 4) + f4];
#pragma unroll
            for (int c = 0; c < 4; ++c) {
                qnv[c] = fmaf(vq[c].x, vq[c].x, qnv[c]);
                qnv[c] = fmaf(vq[c].y, vq[c].y, qnv[c]);
                qnv[c] = fmaf(vq[c].z, vq[c].z, qnv[c]);
                qnv[c] = fmaf(vq[c].w, vq[c].w, qnv[c]);
            }
            float4 xr[RPB];
#pragma unroll
            for (int r = 0; r < RPB; ++r) xr[r] = *reinterpret_cast<const float4*>(&xp[r][f4 * 4]);
#pragma unroll
            for (int r = 0; r < RPB; ++r)
#pragma unroll
                for (int c = 0; c < 4; ++c) {
                    acc[r][c] = fmaf(vq[c].x, xr[r].x, acc[r][c]);
                    acc[r][c] = fmaf(vq[c].y, xr[r].y, acc[r][c]);
                    acc[r][c] = fmaf(vq[c].z, xr[r].z, acc[r][c]);
                    acc[r][c] = fmaf(vq[c].w, xr[r].w, acc[r][c]);
                }
        }
    } else {
        for (int f = 0; f < F; ++f) {
            float vq[4];
#pragma unroll
            for (int c = 0; c < 4; ++c) vq[c] = xc[(size_t)(tid + c * 256) * F + f];
#pragma unroll
            for (int c = 0; c < 4; ++c) qnv[c] = fmaf(vq[c], vq[c], qnv[c]);
#pragma unroll
            for (int r = 0; r < RPB; ++r) {
                const float xv = xp[r][f];
#pragma unroll
                for (int c = 0; c < 4; ++c) acc[r][c] = fmaf(vq[c], xv, acc[r][c]);
            }
        }
    }
#pragma unroll
    for (int c = 0; c < 4; ++c) {
        const int q = tid + c * 256;
#pragma unroll
        for (int r = 0; r < RPB; ++r) {
            float d2 = rn[r] + qnv[c] - 2.f * acc[r][c];
            d2 = fmaxf(d2, 0.f);
            dmat[r][q] = (q == pl0 + r) ? SELFM : __float_as_uint(d2);
        }
    }
    __syncthreads();

    // ---- selection: wave w handles rows w and w+4 ----
    unsigned* hw = hist[wave];
#pragma unroll 1
    for (int rr = 0; rr < 2; ++rr) {
        const int r = wave + rr * 4;
        unsigned bits[16];
#pragma unroll
        for (int i = 0; i < 16; ++i) bits[i] = dmat[r][lane + i * 64];
        unsigned am = 0xFFFFu, sm = 0u;
        int R = KNB;
        int bin[16];
#pragma unroll
        for (int i = 0; i < 16; ++i) bin[i] = 0;

#pragma unroll 1
        for (int pass = 0; pass < 10 && R > 0; ++pass) {
            // recompute base/max over active set (marker -> 0 in max)
            unsigned bmin = SELFM, bmax = 0u;
#pragma unroll
            for (int i = 0; i < 16; ++i) {
                if ((am >> i) & 1) {
                    const unsigned b = bits[i];
                    bmin = min(bmin, b);
                    bmax = max(bmax, b == SELFM ? 0u : b);
                }
            }
#pragma unroll
            for (int off = 1; off < 64; off <<= 1) {
                bmin = min(bmin, (unsigned)__shfl_xor((int)bmin, off));
                bmax = max(bmax, (unsigned)__shfl_xor((int)bmax, off));
            }
            if (bmax <= bmin) {
                // all active reals share identical bits -> take R smallest q
#pragma unroll
                for (int i = 0; i < 16; ++i) {
                    if (R > 0) {
                        const bool c2 = ((am >> i) & 1) && (bits[i] == bmin);
                        const unsigned long long mb = __ballot(c2);
                        const int tot = (int)__popcll(mb);
                        if (tot <= R) { if (c2) sm |= 1u << i; R -= tot; }
                        else {
                            const unsigned long long lower = mb & ((1ull << lane) - 1ull);
                            if (c2 && (int)__popcll(lower) < R) sm |= 1u << i;
                            R = 0;
                        }
                    }
                }
                break;
            }
            const unsigned span = bmax - bmin;
            const int lg = 31 - __clz(span);
            const int shift = lg > 8 ? lg - 8 : 0;   // real bins <= 511, no clamp
            // zero hist
#pragma unroll
            for (int j = 0; j < 9; ++j) { const int k2 = lane + j * 64; if (k2 < HPAD) hw[k2] = 0u; }
            // bin actives (marker underflows -> clamps to 511)
#pragma unroll
            for (int i = 0; i < 16; ++i) {
                if ((am >> i) & 1) {
                    const unsigned d = bits[i] - bmin;
                    int b = (int)(d >> shift);
                    b = b > (NBIN - 1) ? (NBIN - 1) : b;
                    bin[i] = b;
                    atomicAdd(&hw[hidx(b)], 1u);
                }
            }
            // scan: lane owns bins [lane*8, lane*8+8)
            unsigned h[8];
            int cnt = 0;
#pragma unroll
            for (int j = 0; j < 8; ++j) { h[j] = hw[hidx(lane * 8 + j)]; cnt += (int)h[j]; }
            int inc = cnt;
#pragma unroll
            for (int off = 1; off < 64; off <<= 1) {
                const int nv = __shfl_up(inc, off);
                if (lane >= off) inc += nv;
            }
            const int pre = inc - cnt;
            if (pre < R && R <= inc) {           // boundary bin in my segment
                int c = pre, bb = -1, cb = 0; unsigned hbv = 0;
#pragma unroll
                for (int j = 0; j < 8; ++j) {
                    if (bb < 0) {
                        if (c + (int)h[j] >= R) { bb = lane * 8 + j; hbv = h[j]; cb = c; }
                        else c += (int)h[j];
                    }
                }
                bcast[wave] = (unsigned)bb | ((unsigned)cb << 10) | (hbv << 16);
            }
            const unsigned pk = bcast[wave];     // same-wave DS ordering
            const int bbin = (int)(pk & 1023u);
            const int cb   = (int)((pk >> 10) & 63u);
            const int hb   = (int)(pk >> 16);
            const int need = R - cb;             // 1..hb
            if (hb == need) {                    // marker provably not in bbin here
#pragma unroll
                for (int i = 0; i < 16; ++i)
                    if (((am >> i) & 1) && bin[i] <= bbin) sm |= 1u << i;
                R = 0;
            } else {
                unsigned nam = 0u;
#pragma unroll
                for (int i = 0; i < 16; ++i) {
                    if ((am >> i) & 1) {
                        if (bin[i] < bbin) sm |= 1u << i;
                        else if (bin[i] == bbin) nam |= 1u << i;
                    }
                }
                am = nam; R = need;
            }
        }
        // fallback (unreachable by construction): deterministic q-order fill
        if (R > 0) {
#pragma unroll
            for (int i = 0; i < 16; ++i) {
                if (R > 0) {
                    const bool c2 = ((am >> i) & 1) && (bits[i] != SELFM);
                    const unsigned long long mb = __ballot(c2);
                    const int tot = (int)__popcll(mb);
                    if (tot <= R) { if (c2) sm |= 1u << i; R -= tot; }
                    else {
                        const unsigned long long lower = mb & ((1ull << lane) - 1ull);
                        if (c2 && (int)__popcll(lower) < R) sm |= 1u << i;
                        R = 0;
                    }
                }
            }
        }

        // emit: prefix over per-lane counts
        const int cnt2 = __popc(sm);
        int inc2 = cnt2;
#pragma unroll
        for (int off = 1; off < 64; off <<= 1) {
            const int nv = __shfl_up(inc2, off);
            if (lane >= off) inc2 += nv;
        }
        int slot = inc2 - cnt2;
        const int total = __shfl(inc2, 63);
        int* out = nbr + (size_t)(cloud * PPTS + pl0 + r) * KNB;
#pragma unroll
        for (int i = 0; i < 16; ++i)
            if (((sm >> i) & 1) && slot < KNB) { out[slot] = cloud * PPTS + lane + i * 64; ++slot; }
        if (lane == 0)
            for (int s = total; s < KNB; ++s) out[s] = cloud * PPTS + pl0 + r;
    }
}

// ---------------------------------------------------------------------------
// Edge GEMM: A = x @ (W_top - W_bot) + b ; Bm = x @ W_bot
// ---------------------------------------------------------------------------
template<int F, int FO>
__global__ __launch_bounds__(256) void edge_gemm_kernel(const float* __restrict__ x,
                                                        const float* __restrict__ W,
                                                        const float* __restrict__ bias,
                                                        float* __restrict__ A,
                                                        float* __restrict__ Bm) {
    constexpr int RT  = 16;
    constexpr int RS  = 256 / FO;
    constexpr int RPT = RT / RS;
    __shared__ float xs[RT][F];
    const int tid = threadIdx.x;
    const int n0  = blockIdx.x * RT;
    for (int i = tid; i < RT * F; i += 256)
        xs[i / F][i % F] = x[(size_t)n0 * F + i];
    __syncthreads();

    const int o  = tid % FO;
    const int r0 = tid / FO;
    float accA[RPT], accB[RPT];
#pragma unroll
    for (int i = 0; i < RPT; ++i) { accA[i] = 0.f; accB[i] = 0.f; }

    for (int f = 0; f < F; ++f) {
        const float wt = W[(size_t)f * FO + o];
        const float wb = W[(size_t)(F + f) * FO + o];
        const float wd = wt - wb;
#pragma unroll
        for (int i = 0; i < RPT; ++i) {
            const float xv = xs[r0 + i * RS][f];
            accA[i] = fmaf(xv, wd, accA[i]);
            accB[i] = fmaf(xv, wb, accB[i]);
        }
    }
    const float bo = bias[o];
#pragma unroll
    for (int i = 0; i < RPT; ++i) {
        const size_t row = (size_t)(n0 + r0 + i * RS);
        A[row * FO + o]  = accA[i] + bo;
        Bm[row * FO + o] = accB[i];
    }
}

// ---------------------------------------------------------------------------
// Combine: x_out[n,o] = relu(A[n,o] + max_k Bm[nbr[n,k],o])
// ---------------------------------------------------------------------------
template<int FO>
__global__ __launch_bounds__(256) void combine_kernel(const float* __restrict__ A,
                                                      const float* __restrict__ Bm,
                                                      const int* __restrict__ nbr,
                                                      float* __restrict__ xout) {
    const int idx = blockIdx.x * 256 + threadIdx.x;
    const int n = idx / FO;
    const int o = idx % FO;
    const int* nb = nbr + (size_t)n * KNB;
    float m = -FLT_MAX;
#pragma unroll 8
    for (int k = 0; k < KNB; ++k)
        m = fmaxf(m, Bm[(size_t)nb[k] * FO + o]);
    const float v = A[idx] + m;
    xout[idx] = v > 0.f ? v : 0.f;
}

// ---------------------------------------------------------------------------
// Classifier + loss
// ---------------------------------------------------------------------------
__global__ __launch_bounds__(256) void classifier_kernel(const float* __restrict__ x,
                                                         const float* __restrict__ Wc,
                                                         const float* __restrict__ bc,
                                                         const int* __restrict__ target,
                                                         float* __restrict__ probs,
                                                         float* __restrict__ lossbuf) {
    const int tid = threadIdx.x;
    const int lane = tid & 63;
    const int n = blockIdx.x * 4 + (tid >> 6);
    const float* xr = x + (size_t)n * 256;
    float logit = -FLT_MAX;
    if (lane < NCLS) {
        float acc = bc[lane];
        for (int f = 0; f < 256; ++f)
            acc = fmaf(xr[f], Wc[f * NCLS + lane], acc);
        logit = acc;
    }
    float m = logit;
#pragma unroll
    for (int off = 32; off; off >>= 1) m = fmaxf(m, __shfl_xor(m, off));
    const float e = (lane < NCLS) ? __expf(logit - m) : 0.f;
    float s = e;
#pragma unroll
    for (int off = 32; off; off >>= 1) s += __shfl_xor(s, off);
    if (lane < NCLS) probs[(size_t)n * NCLS + lane] = e / s;
    const float lt = __shfl(logit, target[n]);
    if (lane == 0) lossbuf[n] = logf(s) - (lt - m);
}

__global__ __launch_bounds__(256) void loss_reduce_kernel(const float* __restrict__ lossbuf,
                                                          float* __restrict__ out) {
    __shared__ float s[256];
    float acc = 0.f;
    for (int i = threadIdx.x; i < NPTS; i += 256) acc += lossbuf[i];
    s[threadIdx.x] = acc;
    __syncthreads();
    for (int off = 128; off; off >>= 1) {
        if (threadIdx.x < off) s[threadIdx.x] += s[threadIdx.x + off];
        __syncthreads();
    }
    if (threadIdx.x == 0) out[0] = s[0] / (float)NPTS;
}

extern "C" void kernel_launch(void* const* d_in, const int* in_sizes, int n_in,
                              void* d_out, int out_size, void* d_ws, size_t ws_size,
                              hipStream_t stream) {
    (void)in_sizes; (void)n_in; (void)out_size; (void)ws_size;
    const float* x_in   = (const float*)d_in[0];
    const int*   target = (const int*)d_in[2];
    const float* W1 = (const float*)d_in[3];
    const float* b1 = (const float*)d_in[4];
    const float* W2 = (const float*)d_in[5];
    const float* b2 = (const float*)d_in[6];
    const float* W3 = (const float*)d_in[7];
    const float* b3 = (const float*)d_in[8];
    const float* Wc = (const float*)d_in[9];
    const float* bc = (const float*)d_in[10];

    // footprint identical to the round-1 PASSING layout (<= 50MB + 64KB)
    char* ws = (char*)d_ws;
    float* X       = (float*)(ws);                                // N*256 f32
    float* A       = (float*)(ws + (size_t)16 * 1024 * 1024);
    float* Bm      = (float*)(ws + (size_t)32 * 1024 * 1024);
    int*   nbr     = (int*)  (ws + (size_t)48 * 1024 * 1024);
    float* lossbuf = (float*)(ws + (size_t)50 * 1024 * 1024);

    float* outF  = (float*)d_out;
    float* probs = outF + 1;

    // ---- layer 1 (3 -> 64) ----
    knn_kernel<3><<<NPTS / RPB, 256, 0, stream>>>(x_in, nbr);
    edge_gemm_kernel<3, 64><<<NPTS / 16, 256, 0, stream>>>(x_in, W1, b1, A, Bm);
    combine_kernel<64><<<NPTS * 64 / 256, 256, 0, stream>>>(A, Bm, nbr, X);

    // ---- layer 2 (64 -> 128) ----
    knn_kernel<64><<<NPTS / RPB, 256, 0, stream>>>(X, nbr);
    edge_gemm_kernel<64, 128><<<NPTS / 16, 256, 0, stream>>>(X, W2, b2, A, Bm);
    combine_kernel<128><<<NPTS * 128 / 256, 256, 0, stream>>>(A, Bm, nbr, X);

    // ---- layer 3 (128 -> 256) ----
    knn_kernel<128><<<NPTS / RPB, 256, 0, stream>>>(X, nbr);
    edge_gemm_kernel<128, 256><<<NPTS / 16, 256, 0, stream>>>(X, W3, b3, A, Bm);
    combine_kernel<256><<<NPTS * 256 / 256, 256, 0, stream>>>(A, Bm, nbr, X);

    // ---- classifier + loss ----
    classifier_kernel<<<NPTS / 4, 256, 0, stream>>>(X, Wc, bc, target, probs, lossbuf);
    loss_reduce_kernel<<<1, 256, 0, stream>>>(lossbuf, outF);
}

// Round 4
// 582.516 us; speedup vs baseline: 2.4109x; 1.0723x over previous
//
#include <hip/hip_runtime.h>
#include <float.h>
#include <math.h>

#define BCLOUDS 16
#define PPTS    1024
#define NPTS    (BCLOUDS * PPTS)
#define KNB     32
#define NCLS    40
#define RPB     8                  // rows per knn block (= waves per block, 1 row/wave)
#define NBIN    512                // histogram bins
#define HPAD    (NBIN + NBIN / 16) // +1 word pad every 16 -> conflict-light scan
#define SELFM   0xFFFFFFFFu        // self marker: above every real distance bit pattern

__device__ __forceinline__ int hidx(int b) { return b + (b >> 4); }

// ---------------------------------------------------------------------------
// kNN: 8 rows/block, 512 threads, 8 waves -> ONE row per wave (halves the
// serial selection chain vs 2 rows/wave). Distances via norm identity
// (self-dots fused in-register), then per-wave histogram radix select with
// per-pass adaptive (base, shift). Invariants: real candidates never clamp;
// self marker never selectable; span shrinks >=256x per pass.
// ---------------------------------------------------------------------------
template<int F>
__global__ __launch_bounds__(512, 4) void knn_kernel(const float* __restrict__ x,
                                                     int* __restrict__ nbr) {
    __shared__ unsigned dmat[RPB][PPTS];
    __shared__ float    xp[RPB][F];
    __shared__ float    rn[RPB];
    __shared__ unsigned hist[RPB][HPAD];
    __shared__ unsigned bcast[RPB];

    const int tid   = threadIdx.x;
    const int lane  = tid & 63;
    const int wave  = tid >> 6;            // 0..7
    const int bpc   = PPTS / RPB;
    const int cloud = blockIdx.x / bpc;
    const int pl0   = (blockIdx.x % bpc) * RPB;
    const float* xc = x + (size_t)cloud * PPTS * F;

    for (int i = tid; i < RPB * F; i += 512)
        xp[i / F][i % F] = xc[(size_t)(pl0 + i / F) * F + (i % F)];
    __syncthreads();
    if (tid < RPB) {
        float s = 0.f;
        for (int f = 0; f < F; ++f) { const float v = xp[tid][f]; s = fmaf(v, v, s); }
        rn[tid] = s;
    }
    __syncthreads();

    // ---- distances: thread owns candidates q = tid + c*512, c<2 ----
    float acc[RPB][2];
    float qnv[2];
#pragma unroll
    for (int c = 0; c < 2; ++c) qnv[c] = 0.f;
#pragma unroll
    for (int r = 0; r < RPB; ++r)
#pragma unroll
        for (int c = 0; c < 2; ++c) acc[r][c] = 0.f;

    if constexpr (F % 4 == 0) {
        const float4* xc4 = reinterpret_cast<const float4*>(xc);
#pragma unroll 2
        for (int f4 = 0; f4 < F / 4; ++f4) {
            float4 vq[2];
#pragma unroll
            for (int c = 0; c < 2; ++c) vq[c] = xc4[(size_t)(tid + c * 512) * (F / 4) + f4];
#pragma unroll
            for (int c = 0; c < 2; ++c) {
                qnv[c] = fmaf(vq[c].x, vq[c].x, qnv[c]);
                qnv[c] = fmaf(vq[c].y, vq[c].y, qnv[c]);
                qnv[c] = fmaf(vq[c].z, vq[c].z, qnv[c]);
                qnv[c] = fmaf(vq[c].w, vq[c].w, qnv[c]);
            }
            float4 xr[RPB];
#pragma unroll
            for (int r = 0; r < RPB; ++r) xr[r] = *reinterpret_cast<const float4*>(&xp[r][f4 * 4]);
#pragma unroll
            for (int r = 0; r < RPB; ++r)
#pragma unroll
                for (int c = 0; c < 2; ++c) {
                    acc[r][c] = fmaf(vq[c].x, xr[r].x, acc[r][c]);
                    acc[r][c] = fmaf(vq[c].y, xr[r].y, acc[r][c]);
                    acc[r][c] = fmaf(vq[c].z, xr[r].z, acc[r][c]);
                    acc[r][c] = fmaf(vq[c].w, xr[r].w, acc[r][c]);
                }
        }
    } else {
        for (int f = 0; f < F; ++f) {
            float vq[2];
#pragma unroll
            for (int c = 0; c < 2; ++c) vq[c] = xc[(size_t)(tid + c * 512) * F + f];
#pragma unroll
            for (int c = 0; c < 2; ++c) qnv[c] = fmaf(vq[c], vq[c], qnv[c]);
#pragma unroll
            for (int r = 0; r < RPB; ++r) {
                const float xv = xp[r][f];
#pragma unroll
                for (int c = 0; c < 2; ++c) acc[r][c] = fmaf(vq[c], xv, acc[r][c]);
            }
        }
    }
#pragma unroll
    for (int c = 0; c < 2; ++c) {
        const int q = tid + c * 512;
#pragma unroll
        for (int r = 0; r < RPB; ++r) {
            float d2 = rn[r] + qnv[c] - 2.f * acc[r][c];
            d2 = fmaxf(d2, 0.f);
            dmat[r][q] = (q == pl0 + r) ? SELFM : __float_as_uint(d2);
        }
    }
    __syncthreads();

    // ---- selection: wave w handles row w (single row -> short serial chain) ----
    unsigned* hw = hist[wave];
    const int r = wave;
    unsigned bits[16];
#pragma unroll
    for (int i = 0; i < 16; ++i) bits[i] = dmat[r][lane + i * 64];
    unsigned am = 0xFFFFu, sm = 0u;
    int R = KNB;
    int bin[16];
#pragma unroll
    for (int i = 0; i < 16; ++i) bin[i] = 0;

#pragma unroll 1
    for (int pass = 0; pass < 10 && R > 0; ++pass) {
        // recompute base/max over active set (marker -> 0 in max)
        unsigned bmin = SELFM, bmax = 0u;
#pragma unroll
        for (int i = 0; i < 16; ++i) {
            if ((am >> i) & 1) {
                const unsigned b = bits[i];
                bmin = min(bmin, b);
                bmax = max(bmax, b == SELFM ? 0u : b);
            }
        }
#pragma unroll
        for (int off = 1; off < 64; off <<= 1) {
            bmin = min(bmin, (unsigned)__shfl_xor((int)bmin, off));
            bmax = max(bmax, (unsigned)__shfl_xor((int)bmax, off));
        }
        if (bmax <= bmin) {
            // all active reals share identical bits -> take R smallest q
#pragma unroll
            for (int i = 0; i < 16; ++i) {
                if (R > 0) {
                    const bool c2 = ((am >> i) & 1) && (bits[i] == bmin);
                    const unsigned long long mb = __ballot(c2);
                    const int tot = (int)__popcll(mb);
                    if (tot <= R) { if (c2) sm |= 1u << i; R -= tot; }
                    else {
                        const unsigned long long lower = mb & ((1ull << lane) - 1ull);
                        if (c2 && (int)__popcll(lower) < R) sm |= 1u << i;
                        R = 0;
                    }
                }
            }
            break;
        }
        const unsigned span = bmax - bmin;
        const int lg = 31 - __clz(span);
        const int shift = lg > 8 ? lg - 8 : 0;   // real bins <= 511, no clamp
        // zero hist
#pragma unroll
        for (int j = 0; j < 9; ++j) { const int k2 = lane + j * 64; if (k2 < HPAD) hw[k2] = 0u; }
        // bin actives (marker underflows -> clamps to 511)
#pragma unroll
        for (int i = 0; i < 16; ++i) {
            if ((am >> i) & 1) {
                const unsigned d = bits[i] - bmin;
                int b = (int)(d >> shift);
                b = b > (NBIN - 1) ? (NBIN - 1) : b;
                bin[i] = b;
                atomicAdd(&hw[hidx(b)], 1u);
            }
        }
        // scan: lane owns bins [lane*8, lane*8+8)
        unsigned h[8];
        int cnt = 0;
#pragma unroll
        for (int j = 0; j < 8; ++j) { h[j] = hw[hidx(lane * 8 + j)]; cnt += (int)h[j]; }
        int inc = cnt;
#pragma unroll
        for (int off = 1; off < 64; off <<= 1) {
            const int nv = __shfl_up(inc, off);
            if (lane >= off) inc += nv;
        }
        const int pre = inc - cnt;
        if (pre < R && R <= inc) {           // boundary bin in my segment
            int c = pre, bb = -1, cb = 0; unsigned hbv = 0;
#pragma unroll
            for (int j = 0; j < 8; ++j) {
                if (bb < 0) {
                    if (c + (int)h[j] >= R) { bb = lane * 8 + j; hbv = h[j]; cb = c; }
                    else c += (int)h[j];
                }
            }
            bcast[wave] = (unsigned)bb | ((unsigned)cb << 10) | (hbv << 16);
        }
        const unsigned pk = bcast[wave];     // same-wave DS ordering
        const int bbin = (int)(pk & 1023u);
        const int cb   = (int)((pk >> 10) & 63u);
        const int hb   = (int)(pk >> 16);
        const int need = R - cb;             // 1..hb
        if (hb == need) {                    // marker provably not in bbin here
#pragma unroll
            for (int i = 0; i < 16; ++i)
                if (((am >> i) & 1) && bin[i] <= bbin) sm |= 1u << i;
            R = 0;
        } else {
            unsigned nam = 0u;
#pragma unroll
            for (int i = 0; i < 16; ++i) {
                if ((am >> i) & 1) {
                    if (bin[i] < bbin) sm |= 1u << i;
                    else if (bin[i] == bbin) nam |= 1u << i;
                }
            }
            am = nam; R = need;
        }
    }
    // fallback (unreachable by construction): deterministic q-order fill
    if (R > 0) {
#pragma unroll
        for (int i = 0; i < 16; ++i) {
            if (R > 0) {
                const bool c2 = ((am >> i) & 1) && (bits[i] != SELFM);
                const unsigned long long mb = __ballot(c2);
                const int tot = (int)__popcll(mb);
                if (tot <= R) { if (c2) sm |= 1u << i; R -= tot; }
                else {
                    const unsigned long long lower = mb & ((1ull << lane) - 1ull);
                    if (c2 && (int)__popcll(lower) < R) sm |= 1u << i;
                    R = 0;
                }
            }
        }
    }

    // emit: prefix over per-lane counts
    const int cnt2 = __popc(sm);
    int inc2 = cnt2;
#pragma unroll
    for (int off = 1; off < 64; off <<= 1) {
        const int nv = __shfl_up(inc2, off);
        if (lane >= off) inc2 += nv;
    }
    int slot = inc2 - cnt2;
    const int total = __shfl(inc2, 63);
    int* out = nbr + (size_t)(cloud * PPTS + pl0 + r) * KNB;
#pragma unroll
    for (int i = 0; i < 16; ++i)
        if (((sm >> i) & 1) && slot < KNB) { out[slot] = cloud * PPTS + lane + i * 64; ++slot; }
    if (lane == 0)
        for (int s = total; s < KNB; ++s) out[s] = cloud * PPTS + pl0 + r;
}

// ---------------------------------------------------------------------------
// Edge GEMM: A = x @ (W_top - W_bot) + b ; Bm = x @ W_bot
// ---------------------------------------------------------------------------
template<int F, int FO>
__global__ __launch_bounds__(256) void edge_gemm_kernel(const float* __restrict__ x,
                                                        const float* __restrict__ W,
                                                        const float* __restrict__ bias,
                                                        float* __restrict__ A,
                                                        float* __restrict__ Bm) {
    constexpr int RT  = 16;
    constexpr int RS  = 256 / FO;
    constexpr int RPT = RT / RS;
    __shared__ float xs[RT][F];
    const int tid = threadIdx.x;
    const int n0  = blockIdx.x * RT;
    for (int i = tid; i < RT * F; i += 256)
        xs[i / F][i % F] = x[(size_t)n0 * F + i];
    __syncthreads();

    const int o  = tid % FO;
    const int r0 = tid / FO;
    float accA[RPT], accB[RPT];
#pragma unroll
    for (int i = 0; i < RPT; ++i) { accA[i] = 0.f; accB[i] = 0.f; }

    for (int f = 0; f < F; ++f) {
        const float wt = W[(size_t)f * FO + o];
        const float wb = W[(size_t)(F + f) * FO + o];
        const float wd = wt - wb;
#pragma unroll
        for (int i = 0; i < RPT; ++i) {
            const float xv = xs[r0 + i * RS][f];
            accA[i] = fmaf(xv, wd, accA[i]);
            accB[i] = fmaf(xv, wb, accB[i]);
        }
    }
    const float bo = bias[o];
#pragma unroll
    for (int i = 0; i < RPT; ++i) {
        const size_t row = (size_t)(n0 + r0 + i * RS);
        A[row * FO + o]  = accA[i] + bo;
        Bm[row * FO + o] = accB[i];
    }
}

// ---------------------------------------------------------------------------
// Combine: x_out[n,o] = relu(A[n,o] + max_k Bm[nbr[n,k],o])
// ---------------------------------------------------------------------------
template<int FO>
__global__ __launch_bounds__(256) void combine_kernel(const float* __restrict__ A,
                                                      const float* __restrict__ Bm,
                                                      const int* __restrict__ nbr,
                                                      float* __restrict__ xout) {
    const int idx = blockIdx.x * 256 + threadIdx.x;
    const int n = idx / FO;
    const int o = idx % FO;
    const int* nb = nbr + (size_t)n * KNB;
    float m = -FLT_MAX;
#pragma unroll 8
    for (int k = 0; k < KNB; ++k)
        m = fmaxf(m, Bm[(size_t)nb[k] * FO + o]);
    const float v = A[idx] + m;
    xout[idx] = v > 0.f ? v : 0.f;
}

// ---------------------------------------------------------------------------
// Classifier + loss
// ---------------------------------------------------------------------------
__global__ __launch_bounds__(256) void classifier_kernel(const float* __restrict__ x,
                                                         const float* __restrict__ Wc,
                                                         const float* __restrict__ bc,
                                                         const int* __restrict__ target,
                                                         float* __restrict__ probs,
                                                         float* __restrict__ lossbuf) {
    const int tid = threadIdx.x;
    const int lane = tid & 63;
    const int n = blockIdx.x * 4 + (tid >> 6);
    const float* xr = x + (size_t)n * 256;
    float logit = -FLT_MAX;
    if (lane < NCLS) {
        float acc = bc[lane];
        for (int f = 0; f < 256; ++f)
            acc = fmaf(xr[f], Wc[f * NCLS + lane], acc);
        logit = acc;
    }
    float m = logit;
#pragma unroll
    for (int off = 32; off; off >>= 1) m = fmaxf(m, __shfl_xor(m, off));
    const float e = (lane < NCLS) ? __expf(logit - m) : 0.f;
    float s = e;
#pragma unroll
    for (int off = 32; off; off >>= 1) s += __shfl_xor(s, off);
    if (lane < NCLS) probs[(size_t)n * NCLS + lane] = e / s;
    const float lt = __shfl(logit, target[n]);
    if (lane == 0) lossbuf[n] = logf(s) - (lt - m);
}

__global__ __launch_bounds__(256) void loss_reduce_kernel(const float* __restrict__ lossbuf,
                                                          float* __restrict__ out) {
    __shared__ float s[256];
    float acc = 0.f;
    for (int i = threadIdx.x; i < NPTS; i += 256) acc += lossbuf[i];
    s[threadIdx.x] = acc;
    __syncthreads();
    for (int off = 128; off; off >>= 1) {
        if (threadIdx.x < off) s[threadIdx.x] += s[threadIdx.x + off];
        __syncthreads();
    }
    if (threadIdx.x == 0) out[0] = s[0] / (float)NPTS;
}

extern "C" void kernel_launch(void* const* d_in, const int* in_sizes, int n_in,
                              void* d_out, int out_size, void* d_ws, size_t ws_size,
                              hipStream_t stream) {
    (void)in_sizes; (void)n_in; (void)out_size; (void)ws_size;
    const float* x_in   = (const float*)d_in[0];
    const int*   target = (const int*)d_in[2];
    const float* W1 = (const float*)d_in[3];
    const float* b1 = (const float*)d_in[4];
    const float* W2 = (const float*)d_in[5];
    const float* b2 = (const float*)d_in[6];
    const float* W3 = (const float*)d_in[7];
    const float* b3 = (const float*)d_in[8];
    const float* Wc = (const float*)d_in[9];
    const float* bc = (const float*)d_in[10];

    char* ws = (char*)d_ws;
    float* X       = (float*)(ws);                                // N*256 f32
    float* A       = (float*)(ws + (size_t)16 * 1024 * 1024);
    float* Bm      = (float*)(ws + (size_t)32 * 1024 * 1024);
    int*   nbr     = (int*)  (ws + (size_t)48 * 1024 * 1024);
    float* lossbuf = (float*)(ws + (size_t)50 * 1024 * 1024);

    float* outF  = (float*)d_out;
    float* probs = outF + 1;

    // ---- layer 1 (3 -> 64) ----
    knn_kernel<3><<<NPTS / RPB, 512, 0, stream>>>(x_in, nbr);
    edge_gemm_kernel<3, 64><<<NPTS / 16, 256, 0, stream>>>(x_in, W1, b1, A, Bm);
    combine_kernel<64><<<NPTS * 64 / 256, 256, 0, stream>>>(A, Bm, nbr, X);

    // ---- layer 2 (64 -> 128) ----
    knn_kernel<64><<<NPTS / RPB, 512, 0, stream>>>(X, nbr);
    edge_gemm_kernel<64, 128><<<NPTS / 16, 256, 0, stream>>>(X, W2, b2, A, Bm);
    combine_kernel<128><<<NPTS * 128 / 256, 256, 0, stream>>>(A, Bm, nbr, X);

    // ---- layer 3 (128 -> 256) ----
    knn_kernel<128><<<NPTS / RPB, 512, 0, stream>>>(X, nbr);
    edge_gemm_kernel<128, 256><<<NPTS / 16, 256, 0, stream>>>(X, W3, b3, A, Bm);
    combine_kernel<256><<<NPTS * 256 / 256, 256, 0, stream>>>(A, Bm, nbr, X);

    // ---- classifier + loss ----
    classifier_kernel<<<NPTS / 4, 256, 0, stream>>>(X, Wc, bc, target, probs, lossbuf);
    loss_reduce_kernel<<<1, 256, 0, stream>>>(lossbuf, outF);
}